// Round 13
// baseline (259.316 us; speedup 1.0000x reference)
//
#include <hip/hip_runtime.h>
#include <math.h>

// Problem: B=8, N=2048, D=512, K=16
// R21: k_simgemm LDS 50.8KB -> 33.8KB (3 -> 4 blocks/CU): orientation-B
// epilogue split into two 64-row phases so the transpose buffer st needs
// only 64x136 and aliases the K-loop's 2nd buffer pair. launch_bounds
// (256,4) caps VGPR at 128 to realize 4 blocks/CU. wm==1 waves recompute
// f2key in phase 2 (pure; avoids 32 extra VGPRs). Arithmetic/output
// bit-identical. Everything else = R20 (topk/R18 frozen, proj swizzled,
// one-wave merge).

#define NTOK 2048
#define DIM 512

typedef __attribute__((ext_vector_type(8))) __bf16 bf16x8;
typedef __attribute__((ext_vector_type(4))) float f32x4;
typedef __attribute__((ext_vector_type(8))) unsigned short ushort8;

#define GLDS(gp, lp)                                                      \
  __builtin_amdgcn_global_load_lds(                                       \
      (const __attribute__((address_space(1))) void*)(gp),                \
      (__attribute__((address_space(3))) void*)(lp), 16, 0, 0)

__device__ __forceinline__ ushort f2b(float f) {  // RNE fp32->bf16
  unsigned u = __float_as_uint(f);
  return (ushort)((u + 0x7fffu + ((u >> 16) & 1u)) >> 16);
}
__device__ __forceinline__ float b2f(ushort h) {
  return __uint_as_float((unsigned)h << 16);
}
__device__ __forceinline__ ushort f2key(float v) {  // fp16 RNE + order map
  union { _Float16 h; ushort u; } cv;
  cv.h = (_Float16)v;
  ushort hb = cv.u;
  return (hb & 0x8000u) ? (ushort)~hb : (ushort)(hb | 0x8000u);
}

// norm: xnb=bf16(x/|x|), xb=bf16(x), inv64=1/|x|, L=x@aw^T+ab (fp32 logits)
__global__ __launch_bounds__(64) void k_norm(const float* __restrict__ x,
                                             const float* __restrict__ aw,
                                             const float* __restrict__ ab,
                                             ushort* __restrict__ xnb,
                                             ushort* __restrict__ xb,
                                             double* __restrict__ inv64,
                                             float* __restrict__ L) {
  int row = blockIdx.x, lane = threadIdx.x;
  const float* xr = x + (size_t)row * DIM;
  float4 a = *(const float4*)&xr[lane * 8];
  float4 b = *(const float4*)&xr[lane * 8 + 4];

  float s[16];
#pragma unroll
  for (int k = 0; k < 16; ++k) {
    const float4 w0 = *(const float4*)&aw[(size_t)k * DIM + lane * 8];
    const float4 w1 = *(const float4*)&aw[(size_t)k * DIM + lane * 8 + 4];
    s[k] = a.x * w0.x + a.y * w0.y + a.z * w0.z + a.w * w0.w + b.x * w1.x +
           b.y * w1.y + b.z * w1.z + b.w * w1.w;
  }
#pragma unroll
  for (int off = 1; off < 64; off <<= 1)
#pragma unroll
    for (int k = 0; k < 16; ++k) s[k] += __shfl_xor(s[k], off);

  double ss = (double)a.x * a.x + (double)a.y * a.y + (double)a.z * a.z +
              (double)a.w * a.w + (double)b.x * b.x + (double)b.y * b.y +
              (double)b.z * b.z + (double)b.w * b.w;
#pragma unroll
  for (int off = 32; off >= 1; off >>= 1) ss += __shfl_xor(ss, off);
  double inv = 1.0 / sqrt(ss);
  if (lane == 0) {
    inv64[row] = inv;
#pragma unroll
    for (int k = 0; k < 16; ++k) L[(size_t)row * 16 + k] = s[k] + ab[k];
  }
  float f = (float)inv;
  size_t o = (size_t)row * DIM + lane * 8;
  ushort4 r0 = {f2b(a.x), f2b(a.y), f2b(a.z), f2b(a.w)};
  ushort4 r1 = {f2b(b.x), f2b(b.y), f2b(b.z), f2b(b.w)};
  *(ushort4*)&xb[o] = r0;
  *(ushort4*)&xb[o + 4] = r1;
  ushort4 n0 = {f2b(a.x * f), f2b(a.y * f), f2b(a.z * f), f2b(a.w * f)};
  ushort4 n1 = {f2b(b.x * f), f2b(b.y * f), f2b(b.z * f), f2b(b.w * f)};
  *(ushort4*)&xnb[o] = n0;
  *(ushort4*)&xnb[o + 4] = n1;
}

__global__ __launch_bounds__(256) void k_castw(const float* __restrict__ a,
                                               const float* __restrict__ b,
                                               ushort* __restrict__ ab,
                                               ushort* __restrict__ bb) {
  int i = (blockIdx.x * 256 + threadIdx.x) * 4;
  float4 va = *(const float4*)&a[i];
  float4 vb = *(const float4*)&b[i];
  ushort4 oa = {f2b(va.x), f2b(va.y), f2b(va.z), f2b(va.w)};
  ushort4 ob = {f2b(vb.x), f2b(vb.y), f2b(vb.z), f2b(vb.w)};
  *(ushort4*)&ab[i] = oa;
  *(ushort4*)&bb[i] = ob;
}

// stage one 128x32 A-tile + B-tile into LDS (4 GLDS/thread, linear dest)
__device__ __forceinline__ void stage2(const ushort* __restrict__ A,
                                       const ushort* __restrict__ B,
                                       ushort* lA, ushort* lB, int rb, int cb,
                                       int kt, int wv, int ln) {
#pragma unroll
  for (int j = 0; j < 2; ++j) {
    int c = j * 256 + wv * 64 + ln;
    int r = c >> 2, seg = c & 3;
    GLDS(A + (size_t)(rb + r) * DIM + kt + seg * 8, lA + c * 8);
    GLDS(B + (size_t)(cb + r) * DIM + kt + seg * 8, lB + c * 8);
  }
}

// read fragments + 16 MFMA for one 32-K step
__device__ __forceinline__ void frag_mfma(const ushort* lA, const ushort* lB,
                                          int wm, int wn, int col, int quad,
                                          f32x4 (&acc)[4][4]) {
  bf16x8 af[4], bf[4];
#pragma unroll
  for (int i = 0; i < 4; ++i) {
    af[i] = *(const bf16x8*)&lA[(wm * 64 + i * 16 + col) * 32 + quad * 8];
    bf[i] = *(const bf16x8*)&lB[(wn * 64 + i * 16 + col) * 32 + quad * 8];
  }
#pragma unroll
  for (int i = 0; i < 4; ++i)
#pragma unroll
    for (int j = 0; j < 4; ++j)
      acc[i][j] =
          __builtin_amdgcn_mfma_f32_16x16x32_bf16(af[i], bf[j], acc[i][j], 0, 0, 0);
}

// key matrix (16-bit) = map(fp16(Xn_z @ Xn_z^T)); symmetric: only upper-
// triangle tiles (ti<=tj) computed, both mirror orientations written.
// K-loop: safe double-buffered prefetch. XCD-chunk swizzle: 136 = 8x17.
// LDS 33.8KB: st is 64x136, two-phase epilogue, aliases lA1/lB1.
__global__ __launch_bounds__(256, 4) void k_simgemm(
    const ushort* __restrict__ Xn, ushort* __restrict__ Skey) {
  __shared__ __align__(16) ushort lA0[128 * 32];
  __shared__ __align__(16) ushort lB0[128 * 32];
  __shared__ __align__(16) ushort buf1[64 * 136];  // K-loop: lA1|lB1; epi: st2
  ushort* lA1 = buf1;
  ushort* lB1 = buf1 + 128 * 32;
  ushort* st2 = buf1;
  int tid = threadIdx.x;
  int z = blockIdx.z;
  const ushort* Xb = Xn + (size_t)z * NTOK * DIM;
  ushort* Sb = Skey + (size_t)z * NTOK * NTOK;
  // XCD-chunk swizzle (bijective: 136 = 8*17) -> contiguous tile chunks
  // per XCD so tiles sharing an A-panel hit the same L2.
  int bid = (blockIdx.x & 7) * 17 + (blockIdx.x >> 3);
  // triangular decode: bid in [0,136) -> (ti, tj), ti <= tj
  int ti = 0, rem = bid;
  while (rem >= 16 - ti) { rem -= 16 - ti; ++ti; }
  int tj = ti + rem;
  int rb = ti * 128, cb = tj * 128;
  int wv = tid >> 6, ln = tid & 63;
  int wm = wv >> 1, wn = wv & 1;
  int col = ln & 15, quad = ln >> 4;
  f32x4 zero = {0.f, 0.f, 0.f, 0.f};
  f32x4 acc[4][4];
#pragma unroll
  for (int i = 0; i < 4; ++i)
#pragma unroll
    for (int j = 0; j < 4; ++j) acc[i][j] = zero;

  stage2(Xb, Xb, lA0, lB0, rb, cb, 0, wv, ln);
  __syncthreads();
#pragma unroll
  for (int kt16 = 0; kt16 < 16; ++kt16) {
    const ushort* cA = (kt16 & 1) ? lA1 : lA0;
    const ushort* cB = (kt16 & 1) ? lB1 : lB0;
    if (kt16 < 15)  // issue next tile's loads FIRST (overlap with compute)
      stage2(Xb, Xb, (kt16 & 1) ? lA0 : lA1, (kt16 & 1) ? lB0 : lB1, rb, cb,
             (kt16 + 1) * 32, wv, ln);
    frag_mfma(cA, cB, wm, wn, col, quad, acc);
    __syncthreads();  // vmcnt(0)+lgkmcnt(0)+barrier: both hazards closed
  }

  // epilogue phase 0: orientation A (all waves); wm==0 waves stage rows
  // 0..63 into st2 for the coalesced orientation-B write.
#pragma unroll
  for (int i = 0; i < 4; ++i)
#pragma unroll
    for (int j = 0; j < 4; ++j) {
      int r0 = wm * 64 + i * 16 + quad * 4;  // local A-row base (4 regs)
      int c = wn * 64 + j * 16 + col;        // local B-row (W column)
      ushort4 kk = {f2key(acc[i][j][0]), f2key(acc[i][j][1]),
                    f2key(acc[i][j][2]), f2key(acc[i][j][3])};
      // orientation A: W[cb+c][rb+r] (symmetric transposed write, direct)
      *(ushort4*)&Sb[(size_t)(cb + c) * NTOK + rb + r0] = kk;
      if (wm == 0) {
        st2[(r0 + 0) * 136 + c] = kk.x;
        st2[(r0 + 1) * 136 + c] = kk.y;
        st2[(r0 + 2) * 136 + c] = kk.z;
        st2[(r0 + 3) * 136 + c] = kk.w;
      }
    }
  __syncthreads();
  // orientation B rows 0..63 — coalesced 256B row segments from LDS
#pragma unroll
  for (int p = 0; p < 4; ++p) {
    int r = p * 16 + (tid >> 4);
    int cs = (tid & 15) * 8;
    ushort8 row = *(const ushort8*)&st2[r * 136 + cs];
    *(ushort8*)&Sb[(size_t)(rb + r) * NTOK + cb + cs] = row;
  }
  __syncthreads();
  // epilogue phase 1: wm==1 waves stage rows 64..127 (recompute f2key —
  // pure function of live acc; avoids 32 extra VGPRs)
  if (wm == 1) {
#pragma unroll
    for (int i = 0; i < 4; ++i)
#pragma unroll
      for (int j = 0; j < 4; ++j) {
        int r0 = i * 16 + quad * 4;  // row - 64
        int c = wn * 64 + j * 16 + col;
        ushort4 kk = {f2key(acc[i][j][0]), f2key(acc[i][j][1]),
                      f2key(acc[i][j][2]), f2key(acc[i][j][3])};
        st2[(r0 + 0) * 136 + c] = kk.x;
        st2[(r0 + 1) * 136 + c] = kk.y;
        st2[(r0 + 2) * 136 + c] = kk.z;
        st2[(r0 + 3) * 136 + c] = kk.w;
      }
  }
  __syncthreads();
  // orientation B rows 64..127
#pragma unroll
  for (int p = 0; p < 4; ++p) {
    int r = p * 16 + (tid >> 4);
    int cs = (tid & 15) * 8;
    ushort8 row = *(const ushort8*)&st2[r * 136 + cs];
    *(ushort8*)&Sb[(size_t)(rb + 64 + r) * NTOK + cb + cs] = row;
  }
}

// out = relu(Mg@Wm^T) + Xg@Wo^T — both GEMMs fused in one prefetched
// K-loop (safe 2-phase). Flat grid of 512 blocks + bijective XCD-chunk
// swizzle (512 = 8*64): id2 contiguous per XCD; rb=id2>>2, cb=id2&3 so
// the 4 blocks sharing an A-panel are adjacent on one XCD's L2.
__global__ __launch_bounds__(256) void k_proj(const ushort* __restrict__ Mg,
                                              const ushort* __restrict__ Wm,
                                              const ushort* __restrict__ Xg,
                                              const ushort* __restrict__ Wo,
                                              float* __restrict__ out) {
  __shared__ __align__(16) ushort lds[32768];  // 8 x (128*32) buffers, 64KB
  ushort* A1a = lds;
  ushort* B1a = lds + 4096;
  ushort* A2a = lds + 8192;
  ushort* B2a = lds + 12288;
  ushort* A1b = lds + 16384;
  ushort* B1b = lds + 20480;
  ushort* A2b = lds + 24576;
  ushort* B2b = lds + 28672;
  int tid = threadIdx.x;
  int id = blockIdx.x;
  int id2 = (id & 7) * 64 + (id >> 3);  // bijective: 512 = 8*64
  int rb = (id2 >> 2) * 128, cb = (id2 & 3) * 128;
  int wv = tid >> 6, ln = tid & 63;
  int wm = wv >> 1, wn = wv & 1;
  int col = ln & 15, quad = ln >> 4;
  f32x4 zero = {0.f, 0.f, 0.f, 0.f};
  f32x4 a1[4][4], a2[4][4];
#pragma unroll
  for (int i = 0; i < 4; ++i)
#pragma unroll
    for (int j = 0; j < 4; ++j) { a1[i][j] = zero; a2[i][j] = zero; }

  stage2(Mg, Wm, A1a, B1a, rb, cb, 0, wv, ln);
  stage2(Xg, Wo, A2a, B2a, rb, cb, 0, wv, ln);
  __syncthreads();
#pragma unroll
  for (int kt16 = 0; kt16 < 16; ++kt16) {
    const bool odd = kt16 & 1;
    const ushort* cA1 = odd ? A1b : A1a;
    const ushort* cB1 = odd ? B1b : B1a;
    const ushort* cA2 = odd ? A2b : A2a;
    const ushort* cB2 = odd ? B2b : B2a;
    if (kt16 < 15) {  // issue next tile's 8 loads first
      stage2(Mg, Wm, odd ? A1a : A1b, odd ? B1a : B1b, rb, cb,
             (kt16 + 1) * 32, wv, ln);
      stage2(Xg, Wo, odd ? A2a : A2b, odd ? B2a : B2b, rb, cb,
             (kt16 + 1) * 32, wv, ln);
    }
    frag_mfma(cA1, cB1, wm, wn, col, quad, a1);
    frag_mfma(cA2, cB2, wm, wn, col, quad, a2);
    __syncthreads();
  }

#pragma unroll
  for (int i = 0; i < 4; ++i)
#pragma unroll
    for (int j = 0; j < 4; ++j)
#pragma unroll
      for (int r = 0; r < 4; ++r) {
        int m = rb + wm * 64 + i * 16 + quad * 4 + r;
        int n = cb + wn * 64 + j * 16 + col;
        out[(size_t)m * DIM + n] = fmaxf(a1[i][j][r], 0.f) + a2[i][j][r];
      }
}

#define TARGET 24

// suffix-scan of a single 256-bucket histogram; every lane of the calling
// wave receives (v, cnt_{v+1}) via in-wave shuffles. (proven R10/R14)
__device__ __forceinline__ void scan_pick(const unsigned* hist, int lane,
                                          int tgt, int* out_v,
                                          unsigned* out_cntv1) {
  uint4 h = *(const uint4*)&hist[lane * 4];
  unsigned s3 = h.w, s2 = h.z + s3, s1 = h.y + s2, s0 = h.x + s1;
  unsigned inc = s0;
#pragma unroll
  for (int off = 1; off < 64; off <<= 1) {
    unsigned o = __shfl_down(inc, off);
    if (lane + off < 64) inc += o;
  }
  unsigned above = inc - s0;  // sum over buckets >= 4*(lane+1)
  int base = lane * 4;
  int vb = -1;
  if (above + s0 >= (unsigned)tgt) vb = base + 0;
  if (above + s1 >= (unsigned)tgt) vb = base + 1;
  if (above + s2 >= (unsigned)tgt) vb = base + 2;
  if (above + s3 >= (unsigned)tgt) vb = base + 3;
  int v = vb;
#pragma unroll
  for (int off = 1; off < 64; off <<= 1) v = max(v, __shfl_xor(v, off));
  unsigned v1 = 0;
  if ((v >> 2) == lane) {
    int k = v & 3;
    v1 = (k == 0) ? above + s1 : (k == 1) ? above + s2
                               : (k == 2) ? above + s3 : above;
  }
  v1 = __shfl(v1, v >> 2);
  *out_v = v;
  *out_cntv1 = v1;
}

// ONE WAVE PER ROW (64 thr/block) — EXACT R18 (proven 80us). Selection =
// R14 single-copy 2-level radix hist + ballot compaction (zero barriers).
// Rescore = half-wave: candidate l>>5, elems (l&31)*16..+15 (2 contiguous
// 512B segments/load-instr), 4 interleaved fp64 accs, 5-level butterfly
// within each 32-lane half. Lanes<32: bitonic -> ref order.
__global__ __launch_bounds__(64) void k_topk(const ushort* __restrict__ simk,
                                             const float* __restrict__ x,
                                             const double* __restrict__ inv64,
                                             int* __restrict__ idx16,
                                             int batch0, int pbm1, int pbsh) {
  int zi = blockIdx.x & pbm1;
  int n = blockIdx.x >> pbsh;
  int batch = batch0 + zi;
  int lane = threadIdx.x;
  __shared__ __align__(16) unsigned hist1[256];
  __shared__ __align__(16) unsigned hist2[256];
  __shared__ int lidx[32];
  __shared__ double vals[32];
  const ushort* srow = simk + ((size_t)zi * NTOK + (size_t)n) * NTOK;
  const float* xrow = x + ((size_t)batch * NTOK + n) * DIM;

  // preload row-n 16-elem fragment at (lane&31)*16 (same for both halves)
  int hl = lane & 31, half = lane >> 5;
  const float* xnb_ = xrow + hl * 16;
  float4 xn0 = *(const float4*)&xnb_[0];
  float4 xn1 = *(const float4*)&xnb_[4];
  float4 xn2 = *(const float4*)&xnb_[8];
  float4 xn3 = *(const float4*)&xnb_[12];
  double dinvn = inv64[(size_t)batch * NTOK + n];

  // load all 2048 keys: 4 x 16B per lane, coalesced
  ushort8 kk[4];
#pragma unroll
  for (int r = 0; r < 4; ++r)
    kk[r] = *(const ushort8*)&srow[(r * 64 + lane) * 8];
  // zero both histograms (same-wave DS ops are in-order)
  hist1[lane] = 0; hist1[lane + 64] = 0;
  hist1[lane + 128] = 0; hist1[lane + 192] = 0;
  hist2[lane] = 0; hist2[lane + 64] = 0;
  hist2[lane + 128] = 0; hist2[lane + 192] = 0;
  // pass 1: high byte
#pragma unroll
  for (int r = 0; r < 4; ++r)
#pragma unroll
    for (int j = 0; j < 8; ++j)
      atomicAdd(&hist1[kk[r][j] >> 8], 1u);
  int v;
  unsigned v1;
  scan_pick(hist1, lane, TARGET, &v, &v1);
  int need = TARGET - (int)v1;
  // pass 2: low byte within boundary bucket
#pragma unroll
  for (int r = 0; r < 4; ++r)
#pragma unroll
    for (int j = 0; j < 8; ++j)
      if ((kk[r][j] >> 8) == v) atomicAdd(&hist2[kk[r][j] & 255], 1u);
  int u;
  unsigned dummy;
  scan_pick(hist2, lane, need, &u, &dummy);
  unsigned thr = (unsigned)((v << 8) | u);
  // ballot compaction (deterministic, index-ascending order)
  int cnt = 0;
  unsigned long long ltmask = (1ull << lane) - 1ull;
#pragma unroll
  for (int r = 0; r < 4; ++r)
#pragma unroll
    for (int j = 0; j < 8; ++j) {
      bool p = (unsigned)kk[r][j] >= thr;
      unsigned long long m = __ballot(p);
      if (p) {
        int pos = cnt + __popcll(m & ltmask);
        if (pos < 32) lidx[pos] = (r * 64 + lane) * 8 + j;
      }
      cnt += __popcll(m);
    }
  int c = cnt < 32 ? cnt : 32;
  // half-wave fp64 rescore: 2 candidates per iteration
  for (int s0 = 0; s0 < c; s0 += 2) {
    int s = s0 + half;
    if (s < c) {
      int m = lidx[s];
      const float* xc = x + ((size_t)batch * NTOK + m) * DIM + hl * 16;
      float4 b0 = *(const float4*)&xc[0];
      float4 b1 = *(const float4*)&xc[4];
      float4 b2 = *(const float4*)&xc[8];
      float4 b3 = *(const float4*)&xc[12];
      double a0 = 0.0, a1 = 0.0, a2 = 0.0, a3 = 0.0;
      a0 = fma((double)xn0.x, (double)b0.x, a0);
      a1 = fma((double)xn0.y, (double)b0.y, a1);
      a2 = fma((double)xn0.z, (double)b0.z, a2);
      a3 = fma((double)xn0.w, (double)b0.w, a3);
      a0 = fma((double)xn1.x, (double)b1.x, a0);
      a1 = fma((double)xn1.y, (double)b1.y, a1);
      a2 = fma((double)xn1.z, (double)b1.z, a2);
      a3 = fma((double)xn1.w, (double)b1.w, a3);
      a0 = fma((double)xn2.x, (double)b2.x, a0);
      a1 = fma((double)xn2.y, (double)b2.y, a1);
      a2 = fma((double)xn2.z, (double)b2.z, a2);
      a3 = fma((double)xn2.w, (double)b2.w, a3);
      a0 = fma((double)xn3.x, (double)b3.x, a0);
      a1 = fma((double)xn3.y, (double)b3.y, a1);
      a2 = fma((double)xn3.z, (double)b3.z, a2);
      a3 = fma((double)xn3.w, (double)b3.w, a3);
      double sacc = (a0 + a1) + (a2 + a3);
      sacc += __shfl_xor(sacc, 1);
      sacc += __shfl_xor(sacc, 2);
      sacc += __shfl_xor(sacc, 4);
      sacc += __shfl_xor(sacc, 8);
      sacc += __shfl_xor(sacc, 16);
      if (hl == 0)
        vals[s] = sacc * dinvn * inv64[(size_t)batch * NTOK + m];
    }
  }
  if (lane < 32) {
    double sv = (lane < c) ? vals[lane] : -1.0e300;
    int si = (lane < c) ? lidx[lane] : 0x7FFFFFFF;
#pragma unroll
    for (int k = 2; k <= 32; k <<= 1) {
#pragma unroll
      for (int jj = k >> 1; jj > 0; jj >>= 1) {
        double ov = __shfl_xor(sv, jj);
        int oi = __shfl_xor(si, jj);
        bool lower = (lane & jj) == 0;
        bool desc = (lane & k) == 0;
        bool takeFirst = (lower == desc);
        bool otherFirst = (ov > sv) || (ov == sv && oi < si);
        if (takeFirst == otherFirst) { sv = ov; si = oi; }
      }
    }
    if (lane < 16) idx16[((size_t)batch * NTOK + n) * 16 + lane] = si;
  }
}

// ONE WAVE PER ROW. Lanes 0-15: mutual check + softmax (one copy, 4-level
// group shuffles); LDS broadcast is same-wave in-order (no barrier). All
// 64 lanes: aggregate 8 elements each (ushort8, coalesced 1KB per row).
__global__ __launch_bounds__(64) void k_merge(const ushort* __restrict__ xb,
                                              const int* __restrict__ idx16,
                                              const float* __restrict__ L,
                                              ushort* __restrict__ mergedb) {
  int b = blockIdx.x & 7;
  int n = blockIdx.x >> 3;
  int row = (b << 11) | n;
  int lane = threadIdx.x;
  __shared__ float ps[16];
  __shared__ int ms[16];
  if (lane < 16) {
    int m = idx16[(size_t)row * 16 + lane];
    const int* mrow = idx16 + (size_t)(b * NTOK + m) * 16;
    int4 q0 = *(const int4*)&mrow[0];
    int4 q1 = *(const int4*)&mrow[4];
    int4 q2 = *(const int4*)&mrow[8];
    int4 q3 = *(const int4*)&mrow[12];
    bool mut = (q0.x == n) | (q0.y == n) | (q0.z == n) | (q0.w == n) |
               (q1.x == n) | (q1.y == n) | (q1.z == n) | (q1.w == n) |
               (q2.x == n) | (q2.y == n) | (q2.z == n) | (q2.w == n) |
               (q3.x == n) | (q3.y == n) | (q3.z == n) | (q3.w == n);
    float l = mut ? L[(size_t)row * 16 + lane] : -__builtin_inff();
    float mx = l;
#pragma unroll
    for (int off = 1; off < 16; off <<= 1) mx = fmaxf(mx, __shfl_xor(mx, off));
    float e = mut ? __expf(l - mx) : 0.0f;
    float den = e;
#pragma unroll
    for (int off = 1; off < 16; off <<= 1) den += __shfl_xor(den, off);
    ps[lane] = e / den;
    ms[lane] = m;
  }
  // same wave: lanes >=16 see ps/ms writes in order; no barrier needed
  float acc[8] = {0.f, 0.f, 0.f, 0.f, 0.f, 0.f, 0.f, 0.f};
#pragma unroll
  for (int k = 0; k < 16; ++k) {
    float pk = ps[k];
    if (pk != 0.0f) {  // uniform across wave
      ushort8 vv =
          *(const ushort8*)&xb[(size_t)(b * NTOK + ms[k]) * DIM + lane * 8];
#pragma unroll
      for (int e = 0; e < 8; ++e) acc[e] = fmaf(pk, b2f(vv[e]), acc[e]);
    }
  }
  ushort8 o8;
#pragma unroll
  for (int e = 0; e < 8; ++e) o8[e] = f2b(acc[e]);
  *(ushort8*)&mergedb[(size_t)row * DIM + lane * 8] = o8;
}

extern "C" void kernel_launch(void* const* d_in, const int* in_sizes, int n_in,
                              void* d_out, int out_size, void* d_ws,
                              size_t ws_size, hipStream_t stream) {
  const float* x = (const float*)d_in[0];
  const float* attn_w = (const float*)d_in[1];
  const float* attn_b = (const float*)d_in[2];
  const float* w_merged = (const float*)d_in[3];
  const float* w_orig = (const float*)d_in[4];
  float* out = (float*)d_out;

  char* w = (char*)d_ws;
  ushort* xnb = (ushort*)(w);                 // 16,777,216
  ushort* xb = (ushort*)(w + 16777216);       // 16,777,216
  double* inv64 = (double*)(w + 33554432);    //    131,072
  ushort* wmb = (ushort*)(w + 33685504);      //    524,288
  ushort* wob = (ushort*)(w + 34209792);      //    524,288
  int* idx16 = (int*)(w + 34734080);          //  1,048,576
  float* L = (float*)(w + 35782656);          //  1,048,576 (logits)
  ushort* simk = (ushort*)(w + 36831232);     //  pb x 8,388,608 (16-bit keys)
  ushort* mergedb = (ushort*)(w + 36831232);  // alias: simk dead after topk

  size_t fixed = 36831232ull, per = 8388608ull;
  int pb = 1, pbsh = 0;
  if (ws_size >= fixed + 8 * per) { pb = 8; pbsh = 3; }
  else if (ws_size >= fixed + 4 * per) { pb = 4; pbsh = 2; }
  else if (ws_size >= fixed + 2 * per) { pb = 2; pbsh = 1; }

  k_norm<<<16384, 64, 0, stream>>>(x, attn_w, attn_b, xnb, xb, inv64, L);
  k_castw<<<256, 256, 0, stream>>>(w_merged, w_orig, wmb, wob);
  for (int b = 0; b < 8; b += pb) {
    k_simgemm<<<dim3(136, 1, pb), 256, 0, stream>>>(
        xnb + (size_t)b * NTOK * DIM, simk);
    k_topk<<<NTOK * pb, 64, 0, stream>>>(simk, x, inv64, idx16, b, pb - 1,
                                         pbsh);
  }
  k_merge<<<16384, 64, 0, stream>>>(xb, idx16, L, mergedb);
  k_proj<<<512, 256, 0, stream>>>(mergedb, wmb, xb, wob, out);
}

// Round 14
// 252.809 us; speedup vs baseline: 1.0257x; 1.0257x over previous
//
#include <hip/hip_runtime.h>
#include <math.h>

// Problem: B=8, N=2048, D=512, K=16
// R22: consolidation. simgemm reverted to EXACT R20 (R21's LDS-shrink
// epilogue was neutral-to-negative). k_castw folded into k_norm as extra
// grid blocks (>=16384): one fewer launch, arithmetic identical. k_topk =
// R18 frozen (79us; design space bracketed). k_proj = R20 flat+XCD
// swizzle. One-wave merge. Best-measured config + launch consolidation.

#define NTOK 2048
#define DIM 512

typedef __attribute__((ext_vector_type(8))) __bf16 bf16x8;
typedef __attribute__((ext_vector_type(4))) float f32x4;
typedef __attribute__((ext_vector_type(8))) unsigned short ushort8;

#define GLDS(gp, lp)                                                      \
  __builtin_amdgcn_global_load_lds(                                       \
      (const __attribute__((address_space(1))) void*)(gp),                \
      (__attribute__((address_space(3))) void*)(lp), 16, 0, 0)

__device__ __forceinline__ ushort f2b(float f) {  // RNE fp32->bf16
  unsigned u = __float_as_uint(f);
  return (ushort)((u + 0x7fffu + ((u >> 16) & 1u)) >> 16);
}
__device__ __forceinline__ float b2f(ushort h) {
  return __uint_as_float((unsigned)h << 16);
}
__device__ __forceinline__ ushort f2key(float v) {  // fp16 RNE + order map
  union { _Float16 h; ushort u; } cv;
  cv.h = (_Float16)v;
  ushort hb = cv.u;
  return (hb & 0x8000u) ? (ushort)~hb : (ushort)(hb | 0x8000u);
}

// norm: xnb=bf16(x/|x|), xb=bf16(x), inv64=1/|x|, L=x@aw^T+ab (fp32 logits).
// Blocks >= 16384: cast one 256-float chunk of w_merged/w_orig to bf16
// (folded k_castw — saves a launch; arithmetic identical).
__global__ __launch_bounds__(64) void k_norm(const float* __restrict__ x,
                                             const float* __restrict__ aw,
                                             const float* __restrict__ ab,
                                             ushort* __restrict__ xnb,
                                             ushort* __restrict__ xb,
                                             double* __restrict__ inv64,
                                             float* __restrict__ L,
                                             const float* __restrict__ wmf,
                                             const float* __restrict__ wof,
                                             ushort* __restrict__ wmb,
                                             ushort* __restrict__ wob) {
  int row = blockIdx.x, lane = threadIdx.x;
  if (row >= 16384) {  // weight-cast path (1024 blocks x 256 floats each)
    int i = (row - 16384) * 256 + lane * 4;
    float4 va = *(const float4*)&wmf[i];
    float4 vb = *(const float4*)&wof[i];
    ushort4 oa = {f2b(va.x), f2b(va.y), f2b(va.z), f2b(va.w)};
    ushort4 ob = {f2b(vb.x), f2b(vb.y), f2b(vb.z), f2b(vb.w)};
    *(ushort4*)&wmb[i] = oa;
    *(ushort4*)&wob[i] = ob;
    return;
  }
  const float* xr = x + (size_t)row * DIM;
  float4 a = *(const float4*)&xr[lane * 8];
  float4 b = *(const float4*)&xr[lane * 8 + 4];

  float s[16];
#pragma unroll
  for (int k = 0; k < 16; ++k) {
    const float4 w0 = *(const float4*)&aw[(size_t)k * DIM + lane * 8];
    const float4 w1 = *(const float4*)&aw[(size_t)k * DIM + lane * 8 + 4];
    s[k] = a.x * w0.x + a.y * w0.y + a.z * w0.z + a.w * w0.w + b.x * w1.x +
           b.y * w1.y + b.z * w1.z + b.w * w1.w;
  }
#pragma unroll
  for (int off = 1; off < 64; off <<= 1)
#pragma unroll
    for (int k = 0; k < 16; ++k) s[k] += __shfl_xor(s[k], off);

  double ss = (double)a.x * a.x + (double)a.y * a.y + (double)a.z * a.z +
              (double)a.w * a.w + (double)b.x * b.x + (double)b.y * b.y +
              (double)b.z * b.z + (double)b.w * b.w;
#pragma unroll
  for (int off = 32; off >= 1; off >>= 1) ss += __shfl_xor(ss, off);
  double inv = 1.0 / sqrt(ss);
  if (lane == 0) {
    inv64[row] = inv;
#pragma unroll
    for (int k = 0; k < 16; ++k) L[(size_t)row * 16 + k] = s[k] + ab[k];
  }
  float f = (float)inv;
  size_t o = (size_t)row * DIM + lane * 8;
  ushort4 r0 = {f2b(a.x), f2b(a.y), f2b(a.z), f2b(a.w)};
  ushort4 r1 = {f2b(b.x), f2b(b.y), f2b(b.z), f2b(b.w)};
  *(ushort4*)&xb[o] = r0;
  *(ushort4*)&xb[o + 4] = r1;
  ushort4 n0 = {f2b(a.x * f), f2b(a.y * f), f2b(a.z * f), f2b(a.w * f)};
  ushort4 n1 = {f2b(b.x * f), f2b(b.y * f), f2b(b.z * f), f2b(b.w * f)};
  *(ushort4*)&xnb[o] = n0;
  *(ushort4*)&xnb[o + 4] = n1;
}

// stage one 128x32 A-tile + B-tile into LDS (4 GLDS/thread, linear dest)
__device__ __forceinline__ void stage2(const ushort* __restrict__ A,
                                       const ushort* __restrict__ B,
                                       ushort* lA, ushort* lB, int rb, int cb,
                                       int kt, int wv, int ln) {
#pragma unroll
  for (int j = 0; j < 2; ++j) {
    int c = j * 256 + wv * 64 + ln;
    int r = c >> 2, seg = c & 3;
    GLDS(A + (size_t)(rb + r) * DIM + kt + seg * 8, lA + c * 8);
    GLDS(B + (size_t)(cb + r) * DIM + kt + seg * 8, lB + c * 8);
  }
}

// read fragments + 16 MFMA for one 32-K step
__device__ __forceinline__ void frag_mfma(const ushort* lA, const ushort* lB,
                                          int wm, int wn, int col, int quad,
                                          f32x4 (&acc)[4][4]) {
  bf16x8 af[4], bf[4];
#pragma unroll
  for (int i = 0; i < 4; ++i) {
    af[i] = *(const bf16x8*)&lA[(wm * 64 + i * 16 + col) * 32 + quad * 8];
    bf[i] = *(const bf16x8*)&lB[(wn * 64 + i * 16 + col) * 32 + quad * 8];
  }
#pragma unroll
  for (int i = 0; i < 4; ++i)
#pragma unroll
    for (int j = 0; j < 4; ++j)
      acc[i][j] =
          __builtin_amdgcn_mfma_f32_16x16x32_bf16(af[i], bf[j], acc[i][j], 0, 0, 0);
}

// key matrix (16-bit) = map(fp16(Xn_z @ Xn_z^T)); symmetric: only upper-
// triangle tiles (ti<=tj) computed, both mirror orientations written.
// K-loop: safe double-buffered prefetch. XCD-chunk swizzle: 136 = 8x17.
__global__ __launch_bounds__(256) void k_simgemm(const ushort* __restrict__ Xn,
                                                 ushort* __restrict__ Skey) {
  __shared__ __align__(16) ushort lA0[128 * 32];
  __shared__ __align__(16) ushort lB0[128 * 32];
  __shared__ __align__(16) ushort st[128 * 136];  // row stride 136; also buf1
  ushort* lA1 = st;
  ushort* lB1 = st + 128 * 32;
  int tid = threadIdx.x;
  int z = blockIdx.z;
  const ushort* Xb = Xn + (size_t)z * NTOK * DIM;
  ushort* Sb = Skey + (size_t)z * NTOK * NTOK;
  // XCD-chunk swizzle (bijective: 136 = 8*17) -> contiguous tile chunks
  // per XCD so tiles sharing an A-panel hit the same L2.
  int bid = (blockIdx.x & 7) * 17 + (blockIdx.x >> 3);
  // triangular decode: bid in [0,136) -> (ti, tj), ti <= tj
  int ti = 0, rem = bid;
  while (rem >= 16 - ti) { rem -= 16 - ti; ++ti; }
  int tj = ti + rem;
  int rb = ti * 128, cb = tj * 128;
  int wv = tid >> 6, ln = tid & 63;
  int wm = wv >> 1, wn = wv & 1;
  int col = ln & 15, quad = ln >> 4;
  f32x4 zero = {0.f, 0.f, 0.f, 0.f};
  f32x4 acc[4][4];
#pragma unroll
  for (int i = 0; i < 4; ++i)
#pragma unroll
    for (int j = 0; j < 4; ++j) acc[i][j] = zero;

  stage2(Xb, Xb, lA0, lB0, rb, cb, 0, wv, ln);
  __syncthreads();
#pragma unroll
  for (int kt16 = 0; kt16 < 16; ++kt16) {
    const ushort* cA = (kt16 & 1) ? lA1 : lA0;
    const ushort* cB = (kt16 & 1) ? lB1 : lB0;
    if (kt16 < 15)  // issue next tile's loads FIRST (overlap with compute)
      stage2(Xb, Xb, (kt16 & 1) ? lA0 : lA1, (kt16 & 1) ? lB0 : lB1, rb, cb,
             (kt16 + 1) * 32, wv, ln);
    frag_mfma(cA, cB, wm, wn, col, quad, acc);
    __syncthreads();  // vmcnt(0)+lgkmcnt(0)+barrier: both hazards closed
  }

#pragma unroll
  for (int i = 0; i < 4; ++i)
#pragma unroll
    for (int j = 0; j < 4; ++j) {
      int r0 = wm * 64 + i * 16 + quad * 4;  // local A-row base (4 regs)
      int c = wn * 64 + j * 16 + col;        // local B-row (W column)
      ushort4 kk = {f2key(acc[i][j][0]), f2key(acc[i][j][1]),
                    f2key(acc[i][j][2]), f2key(acc[i][j][3])};
      // orientation A: W[cb+c][rb+r] (symmetric transposed write, direct)
      *(ushort4*)&Sb[(size_t)(cb + c) * NTOK + rb + r0] = kk;
      // stage for orientation B
      st[(r0 + 0) * 136 + c] = kk.x;
      st[(r0 + 1) * 136 + c] = kk.y;
      st[(r0 + 2) * 136 + c] = kk.z;
      st[(r0 + 3) * 136 + c] = kk.w;
    }
  __syncthreads();
  // orientation B: W[rb+r][cb+c] — coalesced 256B row segments from LDS
#pragma unroll
  for (int p = 0; p < 8; ++p) {
    int r = p * 16 + (tid >> 4);
    int cs = (tid & 15) * 8;
    ushort8 row = *(const ushort8*)&st[r * 136 + cs];
    *(ushort8*)&Sb[(size_t)(rb + r) * NTOK + cb + cs] = row;
  }
}

// out = relu(Mg@Wm^T) + Xg@Wo^T — both GEMMs fused in one prefetched
// K-loop (safe 2-phase). Flat grid of 512 blocks + bijective XCD-chunk
// swizzle (512 = 8*64): id2 contiguous per XCD; rb=id2>>2, cb=id2&3 so
// the 4 blocks sharing an A-panel are adjacent on one XCD's L2.
__global__ __launch_bounds__(256) void k_proj(const ushort* __restrict__ Mg,
                                              const ushort* __restrict__ Wm,
                                              const ushort* __restrict__ Xg,
                                              const ushort* __restrict__ Wo,
                                              float* __restrict__ out) {
  __shared__ __align__(16) ushort lds[32768];  // 8 x (128*32) buffers, 64KB
  ushort* A1a = lds;
  ushort* B1a = lds + 4096;
  ushort* A2a = lds + 8192;
  ushort* B2a = lds + 12288;
  ushort* A1b = lds + 16384;
  ushort* B1b = lds + 20480;
  ushort* A2b = lds + 24576;
  ushort* B2b = lds + 28672;
  int tid = threadIdx.x;
  int id = blockIdx.x;
  int id2 = (id & 7) * 64 + (id >> 3);  // bijective: 512 = 8*64
  int rb = (id2 >> 2) * 128, cb = (id2 & 3) * 128;
  int wv = tid >> 6, ln = tid & 63;
  int wm = wv >> 1, wn = wv & 1;
  int col = ln & 15, quad = ln >> 4;
  f32x4 zero = {0.f, 0.f, 0.f, 0.f};
  f32x4 a1[4][4], a2[4][4];
#pragma unroll
  for (int i = 0; i < 4; ++i)
#pragma unroll
    for (int j = 0; j < 4; ++j) { a1[i][j] = zero; a2[i][j] = zero; }

  stage2(Mg, Wm, A1a, B1a, rb, cb, 0, wv, ln);
  stage2(Xg, Wo, A2a, B2a, rb, cb, 0, wv, ln);
  __syncthreads();
#pragma unroll
  for (int kt16 = 0; kt16 < 16; ++kt16) {
    const bool odd = kt16 & 1;
    const ushort* cA1 = odd ? A1b : A1a;
    const ushort* cB1 = odd ? B1b : B1a;
    const ushort* cA2 = odd ? A2b : A2a;
    const ushort* cB2 = odd ? B2b : B2a;
    if (kt16 < 15) {  // issue next tile's 8 loads first
      stage2(Mg, Wm, odd ? A1a : A1b, odd ? B1a : B1b, rb, cb,
             (kt16 + 1) * 32, wv, ln);
      stage2(Xg, Wo, odd ? A2a : A2b, odd ? B2a : B2b, rb, cb,
             (kt16 + 1) * 32, wv, ln);
    }
    frag_mfma(cA1, cB1, wm, wn, col, quad, a1);
    frag_mfma(cA2, cB2, wm, wn, col, quad, a2);
    __syncthreads();
  }

#pragma unroll
  for (int i = 0; i < 4; ++i)
#pragma unroll
    for (int j = 0; j < 4; ++j)
#pragma unroll
      for (int r = 0; r < 4; ++r) {
        int m = rb + wm * 64 + i * 16 + quad * 4 + r;
        int n = cb + wn * 64 + j * 16 + col;
        out[(size_t)m * DIM + n] = fmaxf(a1[i][j][r], 0.f) + a2[i][j][r];
      }
}

#define TARGET 24

// suffix-scan of a single 256-bucket histogram; every lane of the calling
// wave receives (v, cnt_{v+1}) via in-wave shuffles. (proven R10/R14)
__device__ __forceinline__ void scan_pick(const unsigned* hist, int lane,
                                          int tgt, int* out_v,
                                          unsigned* out_cntv1) {
  uint4 h = *(const uint4*)&hist[lane * 4];
  unsigned s3 = h.w, s2 = h.z + s3, s1 = h.y + s2, s0 = h.x + s1;
  unsigned inc = s0;
#pragma unroll
  for (int off = 1; off < 64; off <<= 1) {
    unsigned o = __shfl_down(inc, off);
    if (lane + off < 64) inc += o;
  }
  unsigned above = inc - s0;  // sum over buckets >= 4*(lane+1)
  int base = lane * 4;
  int vb = -1;
  if (above + s0 >= (unsigned)tgt) vb = base + 0;
  if (above + s1 >= (unsigned)tgt) vb = base + 1;
  if (above + s2 >= (unsigned)tgt) vb = base + 2;
  if (above + s3 >= (unsigned)tgt) vb = base + 3;
  int v = vb;
#pragma unroll
  for (int off = 1; off < 64; off <<= 1) v = max(v, __shfl_xor(v, off));
  unsigned v1 = 0;
  if ((v >> 2) == lane) {
    int k = v & 3;
    v1 = (k == 0) ? above + s1 : (k == 1) ? above + s2
                               : (k == 2) ? above + s3 : above;
  }
  v1 = __shfl(v1, v >> 2);
  *out_v = v;
  *out_cntv1 = v1;
}

// ONE WAVE PER ROW (64 thr/block) — EXACT R18 (proven 79us). Selection =
// R14 single-copy 2-level radix hist + ballot compaction (zero barriers).
// Rescore = half-wave: candidate l>>5, elems (l&31)*16..+15 (2 contiguous
// 512B segments/load-instr), 4 interleaved fp64 accs, 5-level butterfly
// within each 32-lane half. Lanes<32: bitonic -> ref order.
__global__ __launch_bounds__(64) void k_topk(const ushort* __restrict__ simk,
                                             const float* __restrict__ x,
                                             const double* __restrict__ inv64,
                                             int* __restrict__ idx16,
                                             int batch0, int pbm1, int pbsh) {
  int zi = blockIdx.x & pbm1;
  int n = blockIdx.x >> pbsh;
  int batch = batch0 + zi;
  int lane = threadIdx.x;
  __shared__ __align__(16) unsigned hist1[256];
  __shared__ __align__(16) unsigned hist2[256];
  __shared__ int lidx[32];
  __shared__ double vals[32];
  const ushort* srow = simk + ((size_t)zi * NTOK + (size_t)n) * NTOK;
  const float* xrow = x + ((size_t)batch * NTOK + n) * DIM;

  // preload row-n 16-elem fragment at (lane&31)*16 (same for both halves)
  int hl = lane & 31, half = lane >> 5;
  const float* xnb_ = xrow + hl * 16;
  float4 xn0 = *(const float4*)&xnb_[0];
  float4 xn1 = *(const float4*)&xnb_[4];
  float4 xn2 = *(const float4*)&xnb_[8];
  float4 xn3 = *(const float4*)&xnb_[12];
  double dinvn = inv64[(size_t)batch * NTOK + n];

  // load all 2048 keys: 4 x 16B per lane, coalesced
  ushort8 kk[4];
#pragma unroll
  for (int r = 0; r < 4; ++r)
    kk[r] = *(const ushort8*)&srow[(r * 64 + lane) * 8];
  // zero both histograms (same-wave DS ops are in-order)
  hist1[lane] = 0; hist1[lane + 64] = 0;
  hist1[lane + 128] = 0; hist1[lane + 192] = 0;
  hist2[lane] = 0; hist2[lane + 64] = 0;
  hist2[lane + 128] = 0; hist2[lane + 192] = 0;
  // pass 1: high byte
#pragma unroll
  for (int r = 0; r < 4; ++r)
#pragma unroll
    for (int j = 0; j < 8; ++j)
      atomicAdd(&hist1[kk[r][j] >> 8], 1u);
  int v;
  unsigned v1;
  scan_pick(hist1, lane, TARGET, &v, &v1);
  int need = TARGET - (int)v1;
  // pass 2: low byte within boundary bucket
#pragma unroll
  for (int r = 0; r < 4; ++r)
#pragma unroll
    for (int j = 0; j < 8; ++j)
      if ((kk[r][j] >> 8) == v) atomicAdd(&hist2[kk[r][j] & 255], 1u);
  int u;
  unsigned dummy;
  scan_pick(hist2, lane, need, &u, &dummy);
  unsigned thr = (unsigned)((v << 8) | u);
  // ballot compaction (deterministic, index-ascending order)
  int cnt = 0;
  unsigned long long ltmask = (1ull << lane) - 1ull;
#pragma unroll
  for (int r = 0; r < 4; ++r)
#pragma unroll
    for (int j = 0; j < 8; ++j) {
      bool p = (unsigned)kk[r][j] >= thr;
      unsigned long long m = __ballot(p);
      if (p) {
        int pos = cnt + __popcll(m & ltmask);
        if (pos < 32) lidx[pos] = (r * 64 + lane) * 8 + j;
      }
      cnt += __popcll(m);
    }
  int c = cnt < 32 ? cnt : 32;
  // half-wave fp64 rescore: 2 candidates per iteration
  for (int s0 = 0; s0 < c; s0 += 2) {
    int s = s0 + half;
    if (s < c) {
      int m = lidx[s];
      const float* xc = x + ((size_t)batch * NTOK + m) * DIM + hl * 16;
      float4 b0 = *(const float4*)&xc[0];
      float4 b1 = *(const float4*)&xc[4];
      float4 b2 = *(const float4*)&xc[8];
      float4 b3 = *(const float4*)&xc[12];
      double a0 = 0.0, a1 = 0.0, a2 = 0.0, a3 = 0.0;
      a0 = fma((double)xn0.x, (double)b0.x, a0);
      a1 = fma((double)xn0.y, (double)b0.y, a1);
      a2 = fma((double)xn0.z, (double)b0.z, a2);
      a3 = fma((double)xn0.w, (double)b0.w, a3);
      a0 = fma((double)xn1.x, (double)b1.x, a0);
      a1 = fma((double)xn1.y, (double)b1.y, a1);
      a2 = fma((double)xn1.z, (double)b1.z, a2);
      a3 = fma((double)xn1.w, (double)b1.w, a3);
      a0 = fma((double)xn2.x, (double)b2.x, a0);
      a1 = fma((double)xn2.y, (double)b2.y, a1);
      a2 = fma((double)xn2.z, (double)b2.z, a2);
      a3 = fma((double)xn2.w, (double)b2.w, a3);
      a0 = fma((double)xn3.x, (double)b3.x, a0);
      a1 = fma((double)xn3.y, (double)b3.y, a1);
      a2 = fma((double)xn3.z, (double)b3.z, a2);
      a3 = fma((double)xn3.w, (double)b3.w, a3);
      double sacc = (a0 + a1) + (a2 + a3);
      sacc += __shfl_xor(sacc, 1);
      sacc += __shfl_xor(sacc, 2);
      sacc += __shfl_xor(sacc, 4);
      sacc += __shfl_xor(sacc, 8);
      sacc += __shfl_xor(sacc, 16);
      if (hl == 0)
        vals[s] = sacc * dinvn * inv64[(size_t)batch * NTOK + m];
    }
  }
  if (lane < 32) {
    double sv = (lane < c) ? vals[lane] : -1.0e300;
    int si = (lane < c) ? lidx[lane] : 0x7FFFFFFF;
#pragma unroll
    for (int k = 2; k <= 32; k <<= 1) {
#pragma unroll
      for (int jj = k >> 1; jj > 0; jj >>= 1) {
        double ov = __shfl_xor(sv, jj);
        int oi = __shfl_xor(si, jj);
        bool lower = (lane & jj) == 0;
        bool desc = (lane & k) == 0;
        bool takeFirst = (lower == desc);
        bool otherFirst = (ov > sv) || (ov == sv && oi < si);
        if (takeFirst == otherFirst) { sv = ov; si = oi; }
      }
    }
    if (lane < 16) idx16[((size_t)batch * NTOK + n) * 16 + lane] = si;
  }
}

// ONE WAVE PER ROW. Lanes 0-15: mutual check + softmax (one copy, 4-level
// group shuffles); LDS broadcast is same-wave in-order (no barrier). All
// 64 lanes: aggregate 8 elements each (ushort8, coalesced 1KB per row).
__global__ __launch_bounds__(64) void k_merge(const ushort* __restrict__ xb,
                                              const int* __restrict__ idx16,
                                              const float* __restrict__ L,
                                              ushort* __restrict__ mergedb) {
  int b = blockIdx.x & 7;
  int n = blockIdx.x >> 3;
  int row = (b << 11) | n;
  int lane = threadIdx.x;
  __shared__ float ps[16];
  __shared__ int ms[16];
  if (lane < 16) {
    int m = idx16[(size_t)row * 16 + lane];
    const int* mrow = idx16 + (size_t)(b * NTOK + m) * 16;
    int4 q0 = *(const int4*)&mrow[0];
    int4 q1 = *(const int4*)&mrow[4];
    int4 q2 = *(const int4*)&mrow[8];
    int4 q3 = *(const int4*)&mrow[12];
    bool mut = (q0.x == n) | (q0.y == n) | (q0.z == n) | (q0.w == n) |
               (q1.x == n) | (q1.y == n) | (q1.z == n) | (q1.w == n) |
               (q2.x == n) | (q2.y == n) | (q2.z == n) | (q2.w == n) |
               (q3.x == n) | (q3.y == n) | (q3.z == n) | (q3.w == n);
    float l = mut ? L[(size_t)row * 16 + lane] : -__builtin_inff();
    float mx = l;
#pragma unroll
    for (int off = 1; off < 16; off <<= 1) mx = fmaxf(mx, __shfl_xor(mx, off));
    float e = mut ? __expf(l - mx) : 0.0f;
    float den = e;
#pragma unroll
    for (int off = 1; off < 16; off <<= 1) den += __shfl_xor(den, off);
    ps[lane] = e / den;
    ms[lane] = m;
  }
  // same wave: lanes >=16 see ps/ms writes in order; no barrier needed
  float acc[8] = {0.f, 0.f, 0.f, 0.f, 0.f, 0.f, 0.f, 0.f};
#pragma unroll
  for (int k = 0; k < 16; ++k) {
    float pk = ps[k];
    if (pk != 0.0f) {  // uniform across wave
      ushort8 vv =
          *(const ushort8*)&xb[(size_t)(b * NTOK + ms[k]) * DIM + lane * 8];
#pragma unroll
      for (int e = 0; e < 8; ++e) acc[e] = fmaf(pk, b2f(vv[e]), acc[e]);
    }
  }
  ushort8 o8;
#pragma unroll
  for (int e = 0; e < 8; ++e) o8[e] = f2b(acc[e]);
  *(ushort8*)&mergedb[(size_t)row * DIM + lane * 8] = o8;
}

extern "C" void kernel_launch(void* const* d_in, const int* in_sizes, int n_in,
                              void* d_out, int out_size, void* d_ws,
                              size_t ws_size, hipStream_t stream) {
  const float* x = (const float*)d_in[0];
  const float* attn_w = (const float*)d_in[1];
  const float* attn_b = (const float*)d_in[2];
  const float* w_merged = (const float*)d_in[3];
  const float* w_orig = (const float*)d_in[4];
  float* out = (float*)d_out;

  char* w = (char*)d_ws;
  ushort* xnb = (ushort*)(w);                 // 16,777,216
  ushort* xb = (ushort*)(w + 16777216);       // 16,777,216
  double* inv64 = (double*)(w + 33554432);    //    131,072
  ushort* wmb = (ushort*)(w + 33685504);      //    524,288
  ushort* wob = (ushort*)(w + 34209792);      //    524,288
  int* idx16 = (int*)(w + 34734080);          //  1,048,576
  float* L = (float*)(w + 35782656);          //  1,048,576 (logits)
  ushort* simk = (ushort*)(w + 36831232);     //  pb x 8,388,608 (16-bit keys)
  ushort* mergedb = (ushort*)(w + 36831232);  // alias: simk dead after topk

  size_t fixed = 36831232ull, per = 8388608ull;
  int pb = 1, pbsh = 0;
  if (ws_size >= fixed + 8 * per) { pb = 8; pbsh = 3; }
  else if (ws_size >= fixed + 4 * per) { pb = 4; pbsh = 2; }
  else if (ws_size >= fixed + 2 * per) { pb = 2; pbsh = 1; }

  // 16384 row blocks + 1024 weight-cast blocks (fused k_castw)
  k_norm<<<17408, 64, 0, stream>>>(x, attn_w, attn_b, xnb, xb, inv64, L,
                                   w_merged, w_orig, wmb, wob);
  for (int b = 0; b < 8; b += pb) {
    k_simgemm<<<dim3(136, 1, pb), 256, 0, stream>>>(
        xnb + (size_t)b * NTOK * DIM, simk);
    k_topk<<<NTOK * pb, 64, 0, stream>>>(simk, x, inv64, idx16, b, pb - 1,
                                         pbsh);
  }
  k_merge<<<16384, 64, 0, stream>>>(xb, idx16, L, mergedb);
  k_proj<<<512, 256, 0, stream>>>(mergedb, wmb, xb, wob, out);
}